// Round 8
// baseline (152.211 us; speedup 1.0000x reference)
//
#include <hip/hip_runtime.h>
#include <math.h>

// Attention1D: B=4, L=4096, C=F=64, fp32 in/out.
// scores=(QK^T)/8; softmax over QUERY axis; out = P@V + x = E@(diag(rl)V) + x.
// v8: V stored TILED [b][kt][f][64k] so ALL in-loop loads are dense-permuted
// register gathers (16 lines/instr). k_out/k_stats: zero-LDS zero-barrier
// wave-private loops, counted vmcnt(4), 4 waves/SIMD (launch_bounds 512,4).

#define BB 4
#define LL 4096
#define CC 64
#define C2 0.18033688011112042f  // 0.125 * log2(e)

typedef __attribute__((ext_vector_type(8)))  short bf16x8;
typedef __attribute__((ext_vector_type(4)))  float f32x4;
typedef __attribute__((ext_vector_type(16))) float f32x16;
typedef __attribute__((ext_vector_type(4)))  unsigned int u32x4;

#define MFMA16(a, b, c) __builtin_amdgcn_mfma_f32_16x16x32_bf16(a, b, c, 0, 0, 0)
#define MFMA32(a, b, c) __builtin_amdgcn_mfma_f32_32x32x16_bf16(a, b, c, 0, 0, 0)
#define EXP2(x) __builtin_amdgcn_exp2f(x)

#define GLD4(dst, voff, base, imm) \
    asm volatile("global_load_dwordx4 %0, %1, %2 offset:%c3" \
                 : "=v"(dst) : "v"(voff), "s"(base), "i"(imm))
#define WAITVM(n) asm volatile("s_waitcnt vmcnt(" #n ")")
#define SBAR() __builtin_amdgcn_sched_barrier(0)

static __device__ __forceinline__ bf16x8 asbf(u32x4 v) {
    union { u32x4 a; bf16x8 b; } u; u.a = v; return u.b;
}
static __device__ __forceinline__ unsigned short f2bf(float f) {
    union { float f; unsigned u; } v; v.f = f;
    unsigned r = v.u + 0x7FFFu + ((v.u >> 16) & 1u);
    return (unsigned short)(r >> 16);
}
static __device__ __forceinline__ float bf2f(unsigned short h) {
    union { unsigned u; float f; } v; v.u = ((unsigned)h) << 16; return v.f;
}
static __device__ __forceinline__ bf16x8 pack8(float4 a, float4 b) {
    bf16x8 r;
    r[0] = (short)f2bf(a.x); r[1] = (short)f2bf(a.y);
    r[2] = (short)f2bf(a.z); r[3] = (short)f2bf(a.w);
    r[4] = (short)f2bf(b.x); r[5] = (short)f2bf(b.y);
    r[6] = (short)f2bf(b.z); r[7] = (short)f2bf(b.w);
    return r;
}
static __device__ __forceinline__ unsigned cvtpk(float lo, float hi) {
    unsigned r;
    asm("v_cvt_pk_bf16_f32 %0, %1, %2" : "=v"(r) : "v"(lo), "v"(hi));
    return r;
}

// ---------------- K1: projections via MFMA -> bf16 Q, K, V-tiles ----------------
__global__ __launch_bounds__(512) void k_qkv(
    const float* __restrict__ x,
    const float* __restrict__ Wq, const float* __restrict__ bq,
    const float* __restrict__ Wk, const float* __restrict__ bk,
    const float* __restrict__ Wv, const float* __restrict__ bv,
    unsigned short* __restrict__ Qb, unsigned short* __restrict__ Kb,
    unsigned short* __restrict__ Vt)
{
    __shared__ float Wl[64 * 64];
    __shared__ unsigned short ldsV[64 * 72];
    const int bid = blockIdx.x;
    const int mat = bid % 3;          // 0:Q 1:K 2:V
    const int r0 = (bid / 3) * 64;
    const int tid = threadIdx.x, w = tid >> 6, lane = tid & 63;
    const int c = lane & 15, g = lane >> 4;
    const int rw = (w >> 1) * 16;
    const int c0 = (w & 1) * 32;

    const float* W  = (mat == 0) ? Wq : (mat == 1) ? Wk : Wv;
    const float* bs = (mat == 0) ? bq : (mat == 1) ? bk : bv;

    {   // coalesced W stage
        const float4* wsrc = (const float4*)W;
        float4* wdst = (float4*)Wl;
        wdst[tid] = wsrc[tid];
        wdst[tid + 512] = wsrc[tid + 512];
    }

    const float* xr = x + (size_t)(r0 + rw + c) * CC;
    const bf16x8 ax0 = pack8(((const float4*)xr)[2 * g], ((const float4*)xr)[2 * g + 1]);
    const bf16x8 ax1 = pack8(((const float4*)xr)[8 + 2 * g], ((const float4*)xr)[8 + 2 * g + 1]);
    __syncthreads();

    f32x4 acc0 = {0.f, 0.f, 0.f, 0.f}, acc1 = {0.f, 0.f, 0.f, 0.f};
    {
        const int col = c0 + c;
        bf16x8 b0, b1;
        #pragma unroll
        for (int j = 0; j < 8; ++j) {
            b0[j] = (short)f2bf(Wl[(8 * g + j) * 64 + col]);
            b1[j] = (short)f2bf(Wl[(32 + 8 * g + j) * 64 + col]);
        }
        acc0 = MFMA16(ax0, b0, acc0); acc0 = MFMA16(ax1, b1, acc0);
    }
    {
        const int col = c0 + 16 + c;
        bf16x8 b0, b1;
        #pragma unroll
        for (int j = 0; j < 8; ++j) {
            b0[j] = (short)f2bf(Wl[(8 * g + j) * 64 + col]);
            b1[j] = (short)f2bf(Wl[(32 + 8 * g + j) * 64 + col]);
        }
        acc1 = MFMA16(ax0, b0, acc1); acc1 = MFMA16(ax1, b1, acc1);
    }
    const float bias0 = bs[c0 + c], bias1 = bs[c0 + 16 + c];

    if (mat < 2) {
        unsigned short* dst = (mat == 0) ? Qb : Kb;
        #pragma unroll
        for (int r = 0; r < 4; ++r) {
            const size_t row = (size_t)(r0 + rw + 4 * g + r) * CC;
            dst[row + c0 + c]      = f2bf(acc0[r] + bias0);
            dst[row + c0 + 16 + c] = f2bf(acc1[r] + bias1);
        }
    } else {
        #pragma unroll
        for (int r = 0; r < 4; ++r) {
            const int rowin = rw + 4 * g + r;     // kin within tile
            ldsV[(c0 + c) * 72 + rowin]      = f2bf(acc0[r] + bias0);
            ldsV[(c0 + 16 + c) * 72 + rowin] = f2bf(acc1[r] + bias1);
        }
        __syncthreads();
        const int b = r0 >> 12, kt = (r0 & 4095) >> 6;
        const int f = tid >> 3, jj = tid & 7;
        // Vt[b][kt][f][kin]: contiguous 16B per thread
        *(uint4*)(Vt + (((size_t)(b * 64 + kt) * 64 + f) * 64) + jj * 8) =
            *(const uint4*)(ldsV + f * 72 + jj * 8);
    }
}

// ---------------- K2: column sums -> rescale V-tiles in place ----------------
// grid = B*(L/32) x 512 (8 waves, q-split 8: each wave 512 q = 16 steps of 32).
// Zero in-loop LDS/barriers; 2-set register pipeline, vmcnt(4).
__global__ __launch_bounds__(512, 4) void k_stats(
    const unsigned short* __restrict__ Qb, const unsigned short* __restrict__ Kb,
    unsigned short* __restrict__ Vt)
{
    const int nb = ((blockIdx.x & 7) << 6) | (blockIdx.x >> 3);  // XCD swizzle (512)
    const int b = nb >> 7, kt32 = nb & 127;
    const int kbase = kt32 * 32;
    const int tid = threadIdx.x, w = tid >> 6, lane = tid & 63;
    const int l31 = lane & 31, hi = lane >> 5;

    __shared__ float pl[8][32];
    __shared__ float rls[32];

    // loop-invariant K A-frags (one-time dense-permuted gather)
    const unsigned short* kr = Kb + ((size_t)b * LL + kbase + l31) * CC + 8 * hi;
    const bf16x8 ak0 = *(const bf16x8*)(kr);
    const bf16x8 ak1 = *(const bf16x8*)(kr + 16);
    const bf16x8 ak2 = *(const bf16x8*)(kr + 32);
    const bf16x8 ak3 = *(const bf16x8*)(kr + 48);

    const unsigned short* const sQ = Qb + (size_t)b * LL * CC;
    const int wq0 = w * 512;

    u32x4 qA0, qA1, qA2, qA3, qB0, qB1, qB2, qB3;
    #define QISS(P, si) do { \
        const unsigned vo = (unsigned)(((wq0 + (si) * 32 + l31) * CC + 8 * hi) * 2); \
        GLD4(P##0, vo, sQ, 0);  GLD4(P##1, vo, sQ, 32); \
        GLD4(P##2, vo, sQ, 64); GLD4(P##3, vo, sQ, 96); \
    } while (0)

    QISS(qA, 0); QISS(qB, 1);

    f32x16 lacc = {};
    #define QHALF(P, nsi) do { \
        WAITVM(4); SBAR(); \
        f32x16 T = {}; \
        T = MFMA32(ak0, asbf(P##0), T); \
        T = MFMA32(ak1, asbf(P##1), T); \
        T = MFMA32(ak2, asbf(P##2), T); \
        T = MFMA32(ak3, asbf(P##3), T); \
        SBAR(); \
        QISS(P, (nsi) & 15); \
        _Pragma("unroll") \
        for (int r = 0; r < 16; ++r) lacc[r] += EXP2(T[r] * C2); \
    } while (0)

    for (int s = 0; s < 16; s += 2) {   // tail issues wrap to step 0/1: in-bounds
        QHALF(qA, s + 2);
        QHALF(qB, s + 3);
    }
    #undef QHALF
    #undef QISS

    // reduce over q (32 lanes of each half)
    #pragma unroll
    for (int r = 0; r < 16; ++r) {
        float v = lacc[r];
        v += __shfl_xor(v, 1);  v += __shfl_xor(v, 2);
        v += __shfl_xor(v, 4);  v += __shfl_xor(v, 8);
        v += __shfl_xor(v, 16);
        lacc[r] = v;
    }
    if (l31 == 0) {
        #pragma unroll
        for (int r = 0; r < 16; ++r)
            pl[w][(r & 3) + 8 * (r >> 2) + 4 * hi] = lacc[r];
    }
    __syncthreads();
    if (tid < 32) {
        float L = 0.f;
        #pragma unroll
        for (int ww = 0; ww < 8; ++ww) L += pl[ww][tid];
        rls[tid] = 1.0f / L;
    }
    __syncthreads();

    // rescale V-tile in place: tile kt = kbase/64, kin0 = kbase%64 (0 or 32)
    {
        const int ktv = kt32 >> 1, kin0 = (kt32 & 1) * 32;
        const int f = tid >> 3, j = tid & 7;   // 64 f x 8 j, 4 k each
        unsigned short* vp = Vt + (((size_t)(b * 64 + ktv) * 64 + f) * 64) + kin0 + j * 4;
        ushort4 v = *(const ushort4*)vp;
        v.x = f2bf(bf2f(v.x) * rls[kin0 ? 0 : 0, j * 4 + 0]);
        v.y = f2bf(bf2f(v.y) * rls[j * 4 + 1]);
        v.z = f2bf(bf2f(v.z) * rls[j * 4 + 2]);
        v.w = f2bf(bf2f(v.w) * rls[j * 4 + 3]);
        // fix first element (avoid comma-expr typo risk): recompute
        v.x = f2bf(bf2f(*(const unsigned short*)vp) * 1.0f);  // placeholder overwritten below
        v = *(const ushort4*)vp;
        v.x = f2bf(bf2f(v.x) * rls[j * 4 + 0]);
        v.y = f2bf(bf2f(v.y) * rls[j * 4 + 1]);
        v.z = f2bf(bf2f(v.z) * rls[j * 4 + 2]);
        v.w = f2bf(bf2f(v.w) * rls[j * 4 + 3]);
        *(ushort4*)vp = v;
    }
}

// ---------------- K3: out = E @ V' + x ----------------
// grid = B*(L/32) x 512 (8 waves = 8-way k-split, 16 steps of 32k each).
// Zero in-loop LDS/barriers. Per step: 4 K-GLD4 (dense-permuted) -> S^T
// (4 mfma) -> exp/cvt_pk/shfl_xor(32) -> 4 PV mfma from V-tile GLD4s.
// Counted vmcnt(4) split waits; single-set issue-after-consume staging.
__global__ __launch_bounds__(512, 4) void k_out(
    const float* __restrict__ x,
    const unsigned short* __restrict__ Qb, const unsigned short* __restrict__ Kb,
    const unsigned short* __restrict__ Vt,
    float* __restrict__ out)
{
    const int nb = ((blockIdx.x & 7) << 6) | (blockIdx.x >> 3);  // XCD swizzle (512)
    const int b = nb >> 7, qt = nb & 127;
    const int q0 = qt * 32;
    const int tid = threadIdx.x, ksp = tid >> 6, lane = tid & 63;
    const int l31 = lane & 31, hi = lane >> 5;

    __shared__ float ocomb[32][68];

    // loop-invariant Q B-frags (one-time dense-permuted gather)
    const unsigned short* qr = Qb + ((size_t)b * LL + q0 + l31) * CC + 8 * hi;
    const bf16x8 qb0 = *(const bf16x8*)(qr);
    const bf16x8 qb1 = *(const bf16x8*)(qr + 16);
    const bf16x8 qb2 = *(const bf16x8*)(qr + 32);
    const bf16x8 qb3 = *(const bf16x8*)(qr + 48);

    const unsigned short* const sK = Kb + (size_t)b * LL * CC;
    const unsigned short* const sV = Vt + (size_t)b * 64 * 64 * 64;
    const int kbeg = ksp * 512;

    u32x4 Kst0, Kst1, Kst2, Kst3, Vst0, Vst1, Vst2, Vst3;

    #define KISS(k1) do { \
        const unsigned vo = (unsigned)((((k1) + l31) * CC + 8 * hi) * 2); \
        GLD4(Kst0, vo, sK, 0);  GLD4(Kst1, vo, sK, 32); \
        GLD4(Kst2, vo, sK, 64); GLD4(Kst3, vo, sK, 96); \
    } while (0)
    #define VISS(k1) do { \
        const int _kt = (k1) >> 6, _ki = (k1) & 63; \
        const unsigned vo0 = (unsigned)((((_kt * 64 + l31) * 64) + _ki + 8 * hi) * 2); \
        const unsigned vo1 = vo0 + 32 * 64 * 2; \
        GLD4(Vst0, vo0, sV, 0); GLD4(Vst1, vo0, sV, 32); \
        GLD4(Vst2, vo1, sV, 0); GLD4(Vst3, vo1, sV, 32); \
    } while (0)

    KISS(kbeg); VISS(kbeg);

    f32x16 oacc0 = {}, oacc1 = {};

    for (int s = 0; s < 16; ++s) {
        const int kn = kbeg + ((s + 1) & 15) * 32;   // next step (wraps: in-bounds)
        // ---- S^T: wait K(s) [V(s) still flying] ----
        WAITVM(4); SBAR();
        f32x16 T = {};
        T = MFMA32(asbf(Kst0), qb0, T);
        T = MFMA32(asbf(Kst1), qb1, T);
        T = MFMA32(asbf(Kst2), qb2, T);
        T = MFMA32(asbf(Kst3), qb3, T);
        SBAR();
        KISS(kn);                                    // issue K(s+1)
        // ---- E = exp(S/8), pack to bf16, assemble PV A-frags in-register ----
        const unsigned u0 = cvtpk(EXP2(T[0] * C2),  EXP2(T[1] * C2));
        const unsigned u1 = cvtpk(EXP2(T[2] * C2),  EXP2(T[3] * C2));
        const unsigned u2 = cvtpk(EXP2(T[4] * C2),  EXP2(T[5] * C2));
        const unsigned u3 = cvtpk(EXP2(T[6] * C2),  EXP2(T[7] * C2));
        const unsigned u4 = cvtpk(EXP2(T[8] * C2),  EXP2(T[9] * C2));
        const unsigned u5 = cvtpk(EXP2(T[10] * C2), EXP2(T[11] * C2));
        const unsigned u6 = cvtpk(EXP2(T[12] * C2), EXP2(T[13] * C2));
        const unsigned u7 = cvtpk(EXP2(T[14] * C2), EXP2(T[15] * C2));
        const unsigned t0 = (unsigned)__shfl_xor((int)u0, 32);
        const unsigned t1 = (unsigned)__shfl_xor((int)u1, 32);
        const unsigned t2 = (unsigned)__shfl_xor((int)u2, 32);
        const unsigned t3 = (unsigned)__shfl_xor((int)u3, 32);
        const unsigned t4 = (unsigned)__shfl_xor((int)u4, 32);
        const unsigned t5 = (unsigned)__shfl_xor((int)u5, 32);
        const unsigned t6 = (unsigned)__shfl_xor((int)u6, 32);
        const unsigned t7 = (unsigned)__shfl_xor((int)u7, 32);
        u32x4 f1, f2;
        f1[0] = hi ? t2 : u0;  f1[1] = hi ? t3 : u1;
        f1[2] = hi ? u2 : t0;  f1[3] = hi ? u3 : t1;
        f2[0] = hi ? t6 : u4;  f2[1] = hi ? t7 : u5;
        f2[2] = hi ? u6 : t4;  f2[3] = hi ? u7 : t5;
        // ---- PV: wait V(s) [K(s+1) still flying] ----
        WAITVM(4); SBAR();
        oacc0 = MFMA32(asbf(Vst0), asbf(f1), oacc0);
        oacc0 = MFMA32(asbf(Vst1), asbf(f2), oacc0);
        oacc1 = MFMA32(asbf(Vst2), asbf(f1), oacc1);
        oacc1 = MFMA32(asbf(Vst3), asbf(f2), oacc1);
        SBAR();
        VISS(kn);                                    // issue V(s+1)
    }
    #undef KISS
    #undef VISS

    // combine 8 waves' partial O^T tiles (col=q=l31, row f=(r&3)+8*(r>>2)+4*hi)
    for (int i = tid; i < 32 * 68; i += 512) ((float*)ocomb)[i] = 0.f;
    __syncthreads();
    #pragma unroll
    for (int r = 0; r < 16; ++r) {
        const int fr = (r & 3) + 8 * (r >> 2) + 4 * hi;
        atomicAdd(&ocomb[l31][fr],      oacc0[r]);
        atomicAdd(&ocomb[l31][32 + fr], oacc1[r]);
    }
    __syncthreads();
    {
        const int q = tid >> 4, fc = tid & 15;       // 32 q x 16 float4
        const size_t row = (size_t)b * LL + q0 + q;
        const float4 xv = ((const float4*)(x + row * CC))[fc];
        const float4 ov = *(const float4*)(&ocomb[q][fc * 4]);
        ((float4*)(out + row * CC))[fc] =
            make_float4(xv.x + ov.x, xv.y + ov.y, xv.z + ov.z, xv.w + ov.w);
    }
}

extern "C" void kernel_launch(void* const* d_in, const int* in_sizes, int n_in,
                              void* d_out, int out_size, void* d_ws, size_t ws_size,
                              hipStream_t stream)
{
    const float* x  = (const float*)d_in[0];
    const float* Wq = (const float*)d_in[1];
    const float* bq = (const float*)d_in[2];
    const float* Wk = (const float*)d_in[3];
    const float* bk = (const float*)d_in[4];
    const float* Wv = (const float*)d_in[5];
    const float* bv = (const float*)d_in[6];
    float* out = (float*)d_out;

    const size_t n = (size_t)BB * LL * CC;
    unsigned short* Qb = (unsigned short*)d_ws;
    unsigned short* Kb = Qb + n;
    unsigned short* Vt = Kb + n;

    hipLaunchKernelGGL(k_qkv, dim3(3 * BB * LL / 64), dim3(512), 0, stream,
                       x, Wq, bq, Wk, bk, Wv, bv, Qb, Kb, Vt);
    hipLaunchKernelGGL(k_stats, dim3(BB * (LL / 32)), dim3(512), 0, stream,
                       Qb, Kb, Vt);
    hipLaunchKernelGGL(k_out, dim3(BB * (LL / 32)), dim3(512), 0, stream,
                       x, Qb, Kb, Vt, out);
}

// Round 9
// 109.445 us; speedup vs baseline: 1.3908x; 1.3908x over previous
//
#include <hip/hip_runtime.h>
#include <math.h>

// Attention1D: B=4, L=4096, C=F=64, fp32 in/out.
// scores=(QK^T)/8; softmax over QUERY axis; out = P@V + x = E@(diag(rl)V) + x.
// v9: block-cooperative shared K/V LDS tiles (single-buffered, 68KB -> 2
// blocks/CU), T14 issue-early/write-late coalesced staging, per-wave k-split
// within each step, permlane32_swap E-frag assembly, setprio on MFMA.

#define BB 4
#define LL 4096
#define CC 64
#define C2 0.18033688011112042f  // 0.125 * log2(e)

typedef __attribute__((ext_vector_type(8)))  short bf16x8;
typedef __attribute__((ext_vector_type(4)))  float f32x4;
typedef __attribute__((ext_vector_type(16))) float f32x16;
typedef __attribute__((ext_vector_type(4)))  unsigned int u32x4;

#define MFMA16(a, b, c) __builtin_amdgcn_mfma_f32_16x16x32_bf16(a, b, c, 0, 0, 0)
#define MFMA32(a, b, c) __builtin_amdgcn_mfma_f32_32x32x16_bf16(a, b, c, 0, 0, 0)
#define EXP2(x) __builtin_amdgcn_exp2f(x)

#define GLD4(dst, voff, base, imm) \
    asm volatile("global_load_dwordx4 %0, %1, %2 offset:%c3" \
                 : "=v"(dst) : "v"(voff), "s"(base), "i"(imm))
#define WAITVM0() asm volatile("s_waitcnt vmcnt(0)" ::: "memory")
#define PRIO(n) __builtin_amdgcn_s_setprio(n)

static __device__ __forceinline__ bf16x8 asbf(u32x4 v) {
    union { u32x4 a; bf16x8 b; } u; u.a = v; return u.b;
}
static __device__ __forceinline__ unsigned short f2bf(float f) {
    union { float f; unsigned u; } v; v.f = f;
    unsigned r = v.u + 0x7FFFu + ((v.u >> 16) & 1u);
    return (unsigned short)(r >> 16);
}
static __device__ __forceinline__ float bf2f(unsigned short h) {
    union { unsigned u; float f; } v; v.u = ((unsigned)h) << 16; return v.f;
}
static __device__ __forceinline__ bf16x8 pack8(float4 a, float4 b) {
    bf16x8 r;
    r[0] = (short)f2bf(a.x); r[1] = (short)f2bf(a.y);
    r[2] = (short)f2bf(a.z); r[3] = (short)f2bf(a.w);
    r[4] = (short)f2bf(b.x); r[5] = (short)f2bf(b.y);
    r[6] = (short)f2bf(b.z); r[7] = (short)f2bf(b.w);
    return r;
}
static __device__ __forceinline__ unsigned cvtpk(float lo, float hi) {
    unsigned r;
    asm("v_cvt_pk_bf16_f32 %0, %1, %2" : "=v"(r) : "v"(lo), "v"(hi));
    return r;
}
static __device__ __forceinline__ bf16x8 lds_frag(const unsigned short* p) {
    union { uint2 u[2]; bf16x8 b; } t;
    t.u[0] = *(const uint2*)(p);
    t.u[1] = *(const uint2*)(p + 4);
    return t.b;
}
static __device__ __forceinline__ void lds_put(unsigned short* p, u32x4 v) {
    *(uint2*)(p)     = make_uint2(v[0], v[1]);
    *(uint2*)(p + 4) = make_uint2(v[2], v[3]);
}

// ---------------- K1: projections via MFMA -> bf16 Q, K, V-tiles ----------------
__global__ __launch_bounds__(512) void k_qkv(
    const float* __restrict__ x,
    const float* __restrict__ Wq, const float* __restrict__ bq,
    const float* __restrict__ Wk, const float* __restrict__ bk,
    const float* __restrict__ Wv, const float* __restrict__ bv,
    unsigned short* __restrict__ Qb, unsigned short* __restrict__ Kb,
    unsigned short* __restrict__ Vt)
{
    __shared__ float Wl[64 * 64];
    __shared__ unsigned short ldsV[64 * 72];
    const int bid = blockIdx.x;
    const int mat = bid % 3;          // 0:Q 1:K 2:V
    const int r0 = (bid / 3) * 64;
    const int tid = threadIdx.x, w = tid >> 6, lane = tid & 63;
    const int c = lane & 15, g = lane >> 4;
    const int rw = (w >> 1) * 16;
    const int c0 = (w & 1) * 32;

    const float* W  = (mat == 0) ? Wq : (mat == 1) ? Wk : Wv;
    const float* bs = (mat == 0) ? bq : (mat == 1) ? bk : bv;

    {   // coalesced W stage
        const float4* wsrc = (const float4*)W;
        float4* wdst = (float4*)Wl;
        wdst[tid] = wsrc[tid];
        wdst[tid + 512] = wsrc[tid + 512];
    }

    const float* xr = x + (size_t)(r0 + rw + c) * CC;
    const bf16x8 ax0 = pack8(((const float4*)xr)[2 * g], ((const float4*)xr)[2 * g + 1]);
    const bf16x8 ax1 = pack8(((const float4*)xr)[8 + 2 * g], ((const float4*)xr)[8 + 2 * g + 1]);
    __syncthreads();

    f32x4 acc0 = {0.f, 0.f, 0.f, 0.f}, acc1 = {0.f, 0.f, 0.f, 0.f};
    {
        const int col = c0 + c;
        bf16x8 b0, b1;
        #pragma unroll
        for (int j = 0; j < 8; ++j) {
            b0[j] = (short)f2bf(Wl[(8 * g + j) * 64 + col]);
            b1[j] = (short)f2bf(Wl[(32 + 8 * g + j) * 64 + col]);
        }
        acc0 = MFMA16(ax0, b0, acc0); acc0 = MFMA16(ax1, b1, acc0);
    }
    {
        const int col = c0 + 16 + c;
        bf16x8 b0, b1;
        #pragma unroll
        for (int j = 0; j < 8; ++j) {
            b0[j] = (short)f2bf(Wl[(8 * g + j) * 64 + col]);
            b1[j] = (short)f2bf(Wl[(32 + 8 * g + j) * 64 + col]);
        }
        acc1 = MFMA16(ax0, b0, acc1); acc1 = MFMA16(ax1, b1, acc1);
    }
    const float bias0 = bs[c0 + c], bias1 = bs[c0 + 16 + c];

    if (mat < 2) {
        unsigned short* dst = (mat == 0) ? Qb : Kb;
        #pragma unroll
        for (int r = 0; r < 4; ++r) {
            const size_t row = (size_t)(r0 + rw + 4 * g + r) * CC;
            dst[row + c0 + c]      = f2bf(acc0[r] + bias0);
            dst[row + c0 + 16 + c] = f2bf(acc1[r] + bias1);
        }
    } else {
        #pragma unroll
        for (int r = 0; r < 4; ++r) {
            const int rowin = rw + 4 * g + r;     // kin within tile
            ldsV[(c0 + c) * 72 + rowin]      = f2bf(acc0[r] + bias0);
            ldsV[(c0 + 16 + c) * 72 + rowin] = f2bf(acc1[r] + bias1);
        }
        __syncthreads();
        const int b = r0 >> 12, kt = (r0 & 4095) >> 6;
        const int f = tid >> 3, jj = tid & 7;
        // Vt[b][kt][f][kin]
        *(uint4*)(Vt + (((size_t)(b * 64 + kt) * 64 + f) * 64) + jj * 8) =
            *(const uint4*)(ldsV + f * 72 + jj * 8);
    }
}

// ---------------- K2: column sums -> rescale V-tiles in place ----------------
// grid = B*(L/32) x 512. Block owns 32 k-cols; loops 16 steps of 256 q:
// cooperative coalesced Q-tile stage (single-buf LDS [256][68]) -> each of
// 8 waves MFMAs its 32-q slice -> exp-sum. Issue-early/write-late pipeline.
__global__ __launch_bounds__(512, 4) void k_stats(
    const unsigned short* __restrict__ Qb, const unsigned short* __restrict__ Kb,
    unsigned short* __restrict__ Vt)
{
    const int nb = ((blockIdx.x & 7) << 6) | (blockIdx.x >> 3);  // XCD swizzle (512)
    const int b = nb >> 7, kt32 = nb & 127;
    const int kbase = kt32 * 32;
    const int tid = threadIdx.x, w = tid >> 6, lane = tid & 63;
    const int l31 = lane & 31, hi = lane >> 5;

    __shared__ unsigned short qsm[256 * 68];   // 34.8 KB
    __shared__ float pl[8][32];
    __shared__ float rls[32];

    // loop-invariant K A-frags (one-time gather)
    const unsigned short* kr = Kb + ((size_t)b * LL + kbase + l31) * CC + 8 * hi;
    const bf16x8 ak0 = *(const bf16x8*)(kr);
    const bf16x8 ak1 = *(const bf16x8*)(kr + 16);
    const bf16x8 ak2 = *(const bf16x8*)(kr + 32);
    const bf16x8 ak3 = *(const bf16x8*)(kr + 48);

    const unsigned short* const sQ = Qb + (size_t)b * LL * CC;
    const unsigned gbase = (unsigned)((((tid >> 3) * 64) + (tid & 7) * 8) * 2);
    const int woff = (tid >> 3) * 68 + (tid & 7) * 8;
    const unsigned short* const Qt = qsm + (w * 32 + l31) * 68 + 8 * hi;

    u32x4 S0, S1, S2, S3;
    #define QISS(s_) do { \
        const unsigned vo = gbase + (unsigned)(s_) * 32768u; \
        GLD4(S0, vo, sQ, 0); GLD4(S1, vo + 8192u, sQ, 0); \
        GLD4(S2, vo + 16384u, sQ, 0); GLD4(S3, vo + 24576u, sQ, 0); \
    } while (0)

    QISS(0);
    f32x16 lacc = {};
    for (int s = 0; s < 16; ++s) {
        WAITVM0();                          // stage data in regs
        __syncthreads();                    // prev tile reads done
        lds_put(qsm + woff,         S0);
        lds_put(qsm + woff + 4352,  S1);    // +64*68
        lds_put(qsm + woff + 8704,  S2);
        lds_put(qsm + woff + 13056, S3);
        __syncthreads();                    // tile visible
        if (s < 15) QISS(s + 1);            // fly under compute
        const bf16x8 q0 = lds_frag(Qt);
        const bf16x8 q1 = lds_frag(Qt + 16);
        const bf16x8 q2 = lds_frag(Qt + 32);
        const bf16x8 q3 = lds_frag(Qt + 48);
        f32x16 T = {};
        PRIO(1);
        T = MFMA32(ak0, q0, T); T = MFMA32(ak1, q1, T);
        T = MFMA32(ak2, q2, T); T = MFMA32(ak3, q3, T);
        PRIO(0);
        #pragma unroll
        for (int r = 0; r < 16; ++r) lacc[r] += EXP2(T[r] * C2);
    }
    #undef QISS

    // reduce over q: 32 lanes of each half, then 8 waves
    #pragma unroll
    for (int r = 0; r < 16; ++r) {
        float v = lacc[r];
        v += __shfl_xor(v, 1);  v += __shfl_xor(v, 2);
        v += __shfl_xor(v, 4);  v += __shfl_xor(v, 8);
        v += __shfl_xor(v, 16);
        lacc[r] = v;
    }
    if (l31 == 0) {
        #pragma unroll
        for (int r = 0; r < 16; ++r)
            pl[w][(r & 3) + 8 * (r >> 2) + 4 * hi] = lacc[r];
    }
    __syncthreads();
    if (tid < 32) {
        float L = 0.f;
        #pragma unroll
        for (int ww = 0; ww < 8; ++ww) L += pl[ww][tid];
        rls[tid] = 1.0f / L;
    }
    __syncthreads();

    // rescale V-tile in place: tile ktv = kt32/2, kin0 = (kt32&1)*32
    {
        const int ktv = kt32 >> 1, kin0 = (kt32 & 1) * 32;
        const int f = tid >> 3, j = tid & 7;   // 64 f x 8 j, 4 k each
        unsigned short* vp = Vt + (((size_t)(b * 64 + ktv) * 64 + f) * 64) + kin0 + j * 4;
        ushort4 v = *(const ushort4*)vp;
        v.x = f2bf(bf2f(v.x) * rls[j * 4 + 0]);
        v.y = f2bf(bf2f(v.y) * rls[j * 4 + 1]);
        v.z = f2bf(bf2f(v.z) * rls[j * 4 + 2]);
        v.w = f2bf(bf2f(v.w) * rls[j * 4 + 3]);
        *(ushort4*)vp = v;
    }
}

// ---------------- K3: out = E @ V' + x ----------------
// grid = B*(L/32) x 512 (block = 32 q). 16 steps of 256 k: cooperative
// coalesced stage of shared K[256][68] + V[64][260] tiles (single-buf,
// 68KB -> 2 blocks/CU); each wave computes its 32-k slice: S^T MFMA ->
// exp/cvt_pk/permlane32_swap E-frags -> PV MFMA. 8-way k-split combine.
__global__ __launch_bounds__(512, 4) void k_out(
    const float* __restrict__ x,
    const unsigned short* __restrict__ Qb, const unsigned short* __restrict__ Kb,
    const unsigned short* __restrict__ Vt,
    float* __restrict__ out)
{
    const int nb = ((blockIdx.x & 7) << 6) | (blockIdx.x >> 3);  // XCD swizzle (512)
    const int b = nb >> 7, qt = nb & 127;
    const int q0 = qt * 32;
    const int tid = threadIdx.x, w = tid >> 6, lane = tid & 63;
    const int l31 = lane & 31, hi = lane >> 5;

    __shared__ unsigned short smem[256 * 68 + 64 * 260];  // 68.1 KB (K | V)
    unsigned short* const KT = smem;
    unsigned short* const VT = smem + 256 * 68;

    // loop-invariant Q B-frags (one-time gather)
    const unsigned short* qr = Qb + ((size_t)b * LL + q0 + l31) * CC + 8 * hi;
    const bf16x8 qb0 = *(const bf16x8*)(qr);
    const bf16x8 qb1 = *(const bf16x8*)(qr + 16);
    const bf16x8 qb2 = *(const bf16x8*)(qr + 32);
    const bf16x8 qb3 = *(const bf16x8*)(qr + 48);

    const unsigned short* const sK = Kb + (size_t)b * LL * CC;
    const unsigned short* const sV = Vt + (size_t)b * 64 * 64 * 64;
    const unsigned gbase = (unsigned)((((tid >> 3) * 64) + (tid & 7) * 8) * 2);
    const int wK = (tid >> 3) * 68 + (tid & 7) * 8;
    const int wV = (tid >> 3) * 260 + (tid & 7) * 8;
    const unsigned short* const Ka = KT + (w * 32 + l31) * 68 + 8 * hi;
    const unsigned short* const Va = VT + l31 * 260 + w * 32 + 8 * hi;
    const unsigned short* const Vb2 = VT + (l31 + 32) * 260 + w * 32 + 8 * hi;

    u32x4 S0, S1, S2, S3, S4, S5, S6, S7;
    #define STG(s_) do { \
        const unsigned vo = gbase + (unsigned)(s_) * 32768u; \
        GLD4(S0, vo, sK, 0); GLD4(S1, vo + 8192u, sK, 0); \
        GLD4(S2, vo + 16384u, sK, 0); GLD4(S3, vo + 24576u, sK, 0); \
        GLD4(S4, vo, sV, 0); GLD4(S5, vo + 8192u, sV, 0); \
        GLD4(S6, vo + 16384u, sV, 0); GLD4(S7, vo + 24576u, sV, 0); \
    } while (0)

    STG(0);
    f32x16 oacc0 = {}, oacc1 = {};

    for (int s = 0; s < 16; ++s) {
        WAITVM0();
        __syncthreads();                    // prev tile reads done
        lds_put(KT + wK,         S0);
        lds_put(KT + wK + 4352,  S1);
        lds_put(KT + wK + 8704,  S2);
        lds_put(KT + wK + 13056, S3);
        lds_put(VT + wV,       S4);
        lds_put(VT + wV + 64,  S5);
        lds_put(VT + wV + 128, S6);
        lds_put(VT + wV + 192, S7);
        __syncthreads();                    // tile visible
        if (s < 15) STG(s + 1);             // fly under compute
        // ---- S^T (wave's 32-k slice) ----
        const bf16x8 ak0 = lds_frag(Ka);
        const bf16x8 ak1 = lds_frag(Ka + 16);
        const bf16x8 ak2 = lds_frag(Ka + 32);
        const bf16x8 ak3 = lds_frag(Ka + 48);
        f32x16 T = {};
        PRIO(1);
        T = MFMA32(ak0, qb0, T); T = MFMA32(ak1, qb1, T);
        T = MFMA32(ak2, qb2, T); T = MFMA32(ak3, qb3, T);
        PRIO(0);
        // ---- E = exp2(S*C2), pack, permlane32_swap -> B-frags ----
        unsigned u0 = cvtpk(EXP2(T[0] * C2),  EXP2(T[1] * C2));
        unsigned u1 = cvtpk(EXP2(T[2] * C2),  EXP2(T[3] * C2));
        unsigned u2 = cvtpk(EXP2(T[4] * C2),  EXP2(T[5] * C2));
        unsigned u3 = cvtpk(EXP2(T[6] * C2),  EXP2(T[7] * C2));
        unsigned u4 = cvtpk(EXP2(T[8] * C2),  EXP2(T[9] * C2));
        unsigned u5 = cvtpk(EXP2(T[10] * C2), EXP2(T[11] * C2));
        unsigned u6 = cvtpk(EXP2(T[12] * C2), EXP2(T[13] * C2));
        unsigned u7 = cvtpk(EXP2(T[14] * C2), EXP2(T[15] * C2));
        asm volatile("s_nop 1");
        asm("v_permlane32_swap_b32 %0, %1" : "+v"(u0), "+v"(u2));
        asm("v_permlane32_swap_b32 %0, %1" : "+v"(u1), "+v"(u3));
        asm("v_permlane32_swap_b32 %0, %1" : "+v"(u4), "+v"(u6));
        asm("v_permlane32_swap_b32 %0, %1" : "+v"(u5), "+v"(u7));
        u32x4 f1, f2;
        f1[0] = u0; f1[1] = u1; f1[2] = u2; f1[3] = u3;
        f2[0] = u4; f2[1] = u5; f2[2] = u6; f2[3] = u7;
        // ---- PV ----
        const bf16x8 v00 = lds_frag(Va);
        const bf16x8 v01 = lds_frag(Va + 16);
        const bf16x8 v10 = lds_frag(Vb2);
        const bf16x8 v11 = lds_frag(Vb2 + 16);
        PRIO(1);
        oacc0 = MFMA32(v00, asbf(f1), oacc0);
        oacc0 = MFMA32(v01, asbf(f2), oacc0);
        oacc1 = MFMA32(v10, asbf(f1), oacc1);
        oacc1 = MFMA32(v11, asbf(f2), oacc1);
        PRIO(0);
    }
    #undef STG

    // combine 8 waves' k-split partials (ocomb aliases K tile)
    __syncthreads();
    float* ocomb = (float*)smem;   // [32][68]
    for (int i = tid; i < 32 * 68; i += 512) ocomb[i] = 0.f;
    __syncthreads();
    #pragma unroll
    for (int r = 0; r < 16; ++r) {
        const int fr = (r & 3) + 8 * (r >> 2) + 4 * hi;
        atomicAdd(&ocomb[l31 * 68 + fr],      oacc0[r]);
        atomicAdd(&ocomb[l31 * 68 + 32 + fr], oacc1[r]);
    }
    __syncthreads();
    {
        const int q = tid >> 4, fc = tid & 15;       // 32 q x 16 float4
        const size_t row = (size_t)b * LL + q0 + q;
        const float4 xv = ((const float4*)(x + row * CC))[fc];
        const float4 ov = *(const float4*)(&ocomb[q * 68 + fc * 4]);
        ((float4*)(out + row * CC))[fc] =
            make_float4(xv.x + ov.x, xv.y + ov.y, xv.z + ov.z, xv.w + ov.w);
    }
}

extern "C" void kernel_launch(void* const* d_in, const int* in_sizes, int n_in,
                              void* d_out, int out_size, void* d_ws, size_t ws_size,
                              hipStream_t stream)
{
    const float* x  = (const float*)d_in[0];
    const float* Wq = (const float*)d_in[1];
    const float* bq = (const float*)d_in[2];
    const float* Wk = (const float*)d_in[3];
    const float* bk = (const float*)d_in[4];
    const float* Wv = (const float*)d_in[5];
    const float* bv = (const float*)d_in[6];
    float* out = (float*)d_out;

    const size_t n = (size_t)BB * LL * CC;
    unsigned short* Qb = (unsigned short*)d_ws;
    unsigned short* Kb = Qb + n;
    unsigned short* Vt = Kb + n;

    hipLaunchKernelGGL(k_qkv, dim3(3 * BB * LL / 64), dim3(512), 0, stream,
                       x, Wq, bq, Wk, bk, Wv, bv, Qb, Kb, Vt);
    hipLaunchKernelGGL(k_stats, dim3(BB * (LL / 32)), dim3(512), 0, stream,
                       Qb, Kb, Vt);
    hipLaunchKernelGGL(k_out, dim3(BB * (LL / 32)), dim3(512), 0, stream,
                       x, Qb, Kb, Vt, out);
}

// Round 11
// 104.401 us; speedup vs baseline: 1.4579x; 1.0483x over previous
//
#include <hip/hip_runtime.h>
#include <math.h>

// Attention1D: B=4, L=4096, C=F=64, fp32 in/out.
// scores=(QK^T)/8; softmax over QUERY axis; out = P@V + x = E@(diag(rl)V) + x.
// v11 = v10 with the compile fix: GLD4 base pointers must be BLOCK-uniform
// ("s" constraint); per-wave offsets folded into the 32-bit voffset.
// Zero in-loop barriers; wave-private dbuf LDS tiles; coalesced staging
// 2 steps ahead; V tiled [b][kt32][64f][32kin]; cvt_pk+permlane32_swap.

#define BB 4
#define LL 4096
#define CC 64
#define C2 0.18033688011112042f  // 0.125 * log2(e)

typedef __attribute__((ext_vector_type(8)))  short bf16x8;
typedef __attribute__((ext_vector_type(4)))  float f32x4;
typedef __attribute__((ext_vector_type(16))) float f32x16;
typedef __attribute__((ext_vector_type(4)))  unsigned int u32x4;

#define MFMA16(a, b, c) __builtin_amdgcn_mfma_f32_16x16x32_bf16(a, b, c, 0, 0, 0)
#define MFMA32(a, b, c) __builtin_amdgcn_mfma_f32_32x32x16_bf16(a, b, c, 0, 0, 0)
#define EXP2(x) __builtin_amdgcn_exp2f(x)

#define GLD4(dst, voff, base, imm) \
    asm volatile("global_load_dwordx4 %0, %1, %2 offset:%c3" \
                 : "=v"(dst) : "v"(voff), "s"(base), "i"(imm))
#define WAITVM0() asm volatile("s_waitcnt vmcnt(0)" ::: "memory")
#define SBAR() __builtin_amdgcn_sched_barrier(0)
#define PRIO(n) __builtin_amdgcn_s_setprio(n)

static __device__ __forceinline__ bf16x8 asbf(u32x4 v) {
    union { u32x4 a; bf16x8 b; } u; u.a = v; return u.b;
}
static __device__ __forceinline__ unsigned short f2bf(float f) {
    union { float f; unsigned u; } v; v.f = f;
    unsigned r = v.u + 0x7FFFu + ((v.u >> 16) & 1u);
    return (unsigned short)(r >> 16);
}
static __device__ __forceinline__ float bf2f(unsigned short h) {
    union { unsigned u; float f; } v; v.u = ((unsigned)h) << 16; return v.f;
}
static __device__ __forceinline__ bf16x8 pack8(float4 a, float4 b) {
    bf16x8 r;
    r[0] = (short)f2bf(a.x); r[1] = (short)f2bf(a.y);
    r[2] = (short)f2bf(a.z); r[3] = (short)f2bf(a.w);
    r[4] = (short)f2bf(b.x); r[5] = (short)f2bf(b.y);
    r[6] = (short)f2bf(b.z); r[7] = (short)f2bf(b.w);
    return r;
}
static __device__ __forceinline__ unsigned cvtpk(float lo, float hi) {
    unsigned r;
    asm("v_cvt_pk_bf16_f32 %0, %1, %2" : "=v"(r) : "v"(lo), "v"(hi));
    return r;
}
static __device__ __forceinline__ bf16x8 lds_frag(const unsigned short* p) {
    union { uint2 u[2]; bf16x8 b; } t;
    t.u[0] = *(const uint2*)(p);
    t.u[1] = *(const uint2*)(p + 4);
    return t.b;
}
static __device__ __forceinline__ void lds_put(unsigned short* p, u32x4 v) {
    *(uint2*)(p)     = make_uint2(v[0], v[1]);
    *(uint2*)(p + 4) = make_uint2(v[2], v[3]);
}

// ---------------- K1: projections via MFMA -> bf16 Q, K, V-tiles ----------------
__global__ __launch_bounds__(512) void k_qkv(
    const float* __restrict__ x,
    const float* __restrict__ Wq, const float* __restrict__ bq,
    const float* __restrict__ Wk, const float* __restrict__ bk,
    const float* __restrict__ Wv, const float* __restrict__ bv,
    unsigned short* __restrict__ Qb, unsigned short* __restrict__ Kb,
    unsigned short* __restrict__ Vt)
{
    __shared__ float Wl[64 * 64];
    __shared__ unsigned short ldsV[64 * 72];
    const int bid = blockIdx.x;
    const int mat = bid % 3;          // 0:Q 1:K 2:V
    const int r0 = (bid / 3) * 64;
    const int tid = threadIdx.x, w = tid >> 6, lane = tid & 63;
    const int c = lane & 15, g = lane >> 4;
    const int rw = (w >> 1) * 16;
    const int c0 = (w & 1) * 32;

    const float* W  = (mat == 0) ? Wq : (mat == 1) ? Wk : Wv;
    const float* bs = (mat == 0) ? bq : (mat == 1) ? bk : bv;

    {   // coalesced W stage
        const float4* wsrc = (const float4*)W;
        float4* wdst = (float4*)Wl;
        wdst[tid] = wsrc[tid];
        wdst[tid + 512] = wsrc[tid + 512];
    }

    const float* xr = x + (size_t)(r0 + rw + c) * CC;
    const bf16x8 ax0 = pack8(((const float4*)xr)[2 * g], ((const float4*)xr)[2 * g + 1]);
    const bf16x8 ax1 = pack8(((const float4*)xr)[8 + 2 * g], ((const float4*)xr)[8 + 2 * g + 1]);
    __syncthreads();

    f32x4 acc0 = {0.f, 0.f, 0.f, 0.f}, acc1 = {0.f, 0.f, 0.f, 0.f};
    {
        const int col = c0 + c;
        bf16x8 b0, b1;
        #pragma unroll
        for (int j = 0; j < 8; ++j) {
            b0[j] = (short)f2bf(Wl[(8 * g + j) * 64 + col]);
            b1[j] = (short)f2bf(Wl[(32 + 8 * g + j) * 64 + col]);
        }
        acc0 = MFMA16(ax0, b0, acc0); acc0 = MFMA16(ax1, b1, acc0);
    }
    {
        const int col = c0 + 16 + c;
        bf16x8 b0, b1;
        #pragma unroll
        for (int j = 0; j < 8; ++j) {
            b0[j] = (short)f2bf(Wl[(8 * g + j) * 64 + col]);
            b1[j] = (short)f2bf(Wl[(32 + 8 * g + j) * 64 + col]);
        }
        acc1 = MFMA16(ax0, b0, acc1); acc1 = MFMA16(ax1, b1, acc1);
    }
    const float bias0 = bs[c0 + c], bias1 = bs[c0 + 16 + c];

    if (mat < 2) {
        unsigned short* dst = (mat == 0) ? Qb : Kb;
        #pragma unroll
        for (int r = 0; r < 4; ++r) {
            const size_t row = (size_t)(r0 + rw + 4 * g + r) * CC;
            dst[row + c0 + c]      = f2bf(acc0[r] + bias0);
            dst[row + c0 + 16 + c] = f2bf(acc1[r] + bias1);
        }
    } else {
        #pragma unroll
        for (int r = 0; r < 4; ++r) {
            const int rowin = rw + 4 * g + r;     // k within 64-row group
            ldsV[(c0 + c) * 72 + rowin]      = f2bf(acc0[r] + bias0);
            ldsV[(c0 + 16 + c) * 72 + rowin] = f2bf(acc1[r] + bias1);
        }
        __syncthreads();
        // Vt[b][kt32][f][kin32]: two 4KB tiles per block, fully contiguous
        const int b = r0 >> 12, ktb = (r0 & 4095) >> 5;
        const int h = tid >> 8, f = (tid >> 2) & 63, ch = tid & 3;
        *(uint4*)(Vt + ((size_t)(b * 128 + ktb + h) * 64 + f) * 32 + ch * 8)
            = *(const uint4*)(ldsV + f * 72 + h * 32 + ch * 8);
    }
}

// ---------------- K2: column sums -> rescale V-tiles in place ----------------
// grid = B*(L/32) x 512. Block owns 32 k; wave w owns q in [w*512,(w+1)*512),
// 16 steps of 32q. Wave-private dbuf Q tiles, no in-loop barriers.
__global__ __launch_bounds__(512, 4) void k_stats(
    const unsigned short* __restrict__ Qb, const unsigned short* __restrict__ Kb,
    unsigned short* __restrict__ Vt)
{
    const int nb = ((blockIdx.x & 7) << 6) | (blockIdx.x >> 3);  // XCD swizzle (512)
    const int b = nb >> 7, kt32 = nb & 127;
    const int kbase = kt32 * 32;
    const int tid = threadIdx.x, w = tid >> 6, lane = tid & 63;
    const int l31 = lane & 31, hi = lane >> 5;

    __shared__ unsigned short qsm[8][2][32 * 68];   // 69632 B
    __shared__ float pl[8][32];
    __shared__ float rls[32];

    // loop-invariant K A-frags (one-time gather)
    const unsigned short* kr = Kb + ((size_t)b * LL + kbase + l31) * CC + 8 * hi;
    const bf16x8 ak0 = *(const bf16x8*)(kr);
    const bf16x8 ak1 = *(const bf16x8*)(kr + 16);
    const bf16x8 ak2 = *(const bf16x8*)(kr + 32);
    const bf16x8 ak3 = *(const bf16x8*)(kr + 48);

    const unsigned short* const sQ = Qb + (size_t)b * LL * CC;  // block-uniform base
    const unsigned wqoff = (unsigned)(w * 65536);               // wave's 512-q slab (bytes)
    const int wb = (lane >> 3) * 68 + (lane & 7) * 8;   // LDS write base (+544/it)
    unsigned short* const q0b = &qsm[w][0][0];
    unsigned short* const q1b = &qsm[w][1][0];

    u32x4 S0, S1, S2, S3;
    #define QISS(s_) do { \
        const unsigned vo = wqoff + (unsigned)((s_) * 4096 + lane * 16); \
        GLD4(S0, vo, sQ, 0);    GLD4(S1, vo, sQ, 1024); \
        GLD4(S2, vo, sQ, 2048); GLD4(S3, vo, sQ, 3072); \
    } while (0)
    #define QWR(dst) do { \
        unsigned short* _p = (dst) + wb; \
        lds_put(_p, S0);        lds_put(_p + 544, S1); \
        lds_put(_p + 1088, S2); lds_put(_p + 1632, S3); \
    } while (0)

    QISS(0); WAITVM0(); SBAR(); QWR(q0b); QISS(1);

    f32x16 lacc = {};
    for (int s = 0; s < 16; ++s) {
        const unsigned short* qp = ((s & 1) ? q1b : q0b) + l31 * 68 + hi * 8;
        const bf16x8 b0 = lds_frag(qp);
        const bf16x8 b1 = lds_frag(qp + 16);
        const bf16x8 b2 = lds_frag(qp + 32);
        const bf16x8 b3 = lds_frag(qp + 48);
        f32x16 T = {};
        PRIO(1);
        T = MFMA32(ak0, b0, T); T = MFMA32(ak1, b1, T);
        T = MFMA32(ak2, b2, T); T = MFMA32(ak3, b3, T);
        PRIO(0);
        #pragma unroll
        for (int r = 0; r < 16; ++r) lacc[r] += EXP2(T[r] * C2);
        if (s < 15) {
            WAITVM0(); SBAR();              // tile s+1 regs arrived (flew over compute)
            QWR((s & 1) ? q0b : q1b);
            if (s < 14) QISS(s + 2);
        }
    }
    #undef QISS
    #undef QWR

    // reduce over q: 32 lanes of each half, then 8 waves
    #pragma unroll
    for (int r = 0; r < 16; ++r) {
        float v = lacc[r];
        v += __shfl_xor(v, 1);  v += __shfl_xor(v, 2);
        v += __shfl_xor(v, 4);  v += __shfl_xor(v, 8);
        v += __shfl_xor(v, 16);
        lacc[r] = v;
    }
    if (l31 == 0) {
        #pragma unroll
        for (int r = 0; r < 16; ++r)
            pl[w][(r & 3) + 8 * (r >> 2) + 4 * hi] = lacc[r];
    }
    __syncthreads();
    if (tid < 32) {
        float L = 0.f;
        #pragma unroll
        for (int ww = 0; ww < 8; ++ww) L += pl[ww][tid];
        rls[tid] = 1.0f / L;
    }
    __syncthreads();

    // rescale the kt32 V-tile [64 f][32 kin] in place (4KB contiguous)
    {
        unsigned short* vbase = Vt + ((size_t)(b * 128 + kt32)) * 2048;
        const int kin0 = (tid & 7) * 4;
        ushort4 v = *(const ushort4*)(vbase + tid * 4);
        v.x = f2bf(bf2f(v.x) * rls[kin0 + 0]);
        v.y = f2bf(bf2f(v.y) * rls[kin0 + 1]);
        v.z = f2bf(bf2f(v.z) * rls[kin0 + 2]);
        v.w = f2bf(bf2f(v.w) * rls[kin0 + 3]);
        *(ushort4*)(vbase + tid * 4) = v;
    }
}

// ---------------- K3: out = E @ V' + x ----------------
// grid = B*(L/32) x 512 (block = 32 q). Wave w owns k in [w*512,(w+1)*512),
// 16 steps of 32k. Wave-private dbuf K[32][68] + V[64][36] tiles, no in-loop
// barriers. Per step: 4 S-MFMA -> exp/cvt_pk/permlane32_swap -> 4 PV-MFMA.
__global__ __launch_bounds__(512, 2) void k_out(
    const float* __restrict__ x,
    const unsigned short* __restrict__ Qb, const unsigned short* __restrict__ Kb,
    const unsigned short* __restrict__ Vt,
    float* __restrict__ out)
{
    const int nb = ((blockIdx.x & 7) << 6) | (blockIdx.x >> 3);  // XCD swizzle (512)
    const int b = nb >> 7, qt = nb & 127;
    const int q0 = qt * 32;
    const int tid = threadIdx.x, w = tid >> 6, lane = tid & 63;
    const int l31 = lane & 31, hi = lane >> 5;

    __shared__ unsigned short ksm[8][2][32 * 68];   // 69632 B
    __shared__ unsigned short vsm[8][2][64 * 36];   // 73728 B

    // loop-invariant Q B-frags (one-time gather)
    const unsigned short* qr = Qb + ((size_t)b * LL + q0 + l31) * CC + 8 * hi;
    const bf16x8 qb0 = *(const bf16x8*)(qr);
    const bf16x8 qb1 = *(const bf16x8*)(qr + 16);
    const bf16x8 qb2 = *(const bf16x8*)(qr + 32);
    const bf16x8 qb3 = *(const bf16x8*)(qr + 48);

    const unsigned short* const sK = Kb + (size_t)b * LL * CC;        // block-uniform
    const unsigned short* const sV = Vt + (size_t)b * 128 * 2048;     // block-uniform
    const unsigned wkoff = (unsigned)(w * 65536);   // wave's 512-k K slab (bytes)
    const unsigned wvoff = (unsigned)(w * 65536);   // wave's 16 V tiles (bytes)
    const int kwb = (lane >> 3) * 68 + (lane & 7) * 8;   // K write base (+544/it)
    const int vwb = (lane >> 2) * 36 + (lane & 3) * 8;   // V write base (+576/it)

    u32x4 K0, K1, K2, K3, V0, V1, V2, V3;
    #define KISS(s_) do { \
        const unsigned vo = wkoff + (unsigned)((s_) * 4096 + lane * 16); \
        GLD4(K0, vo, sK, 0);    GLD4(K1, vo, sK, 1024); \
        GLD4(K2, vo, sK, 2048); GLD4(K3, vo, sK, 3072); \
    } while (0)
    #define VISS(s_) do { \
        const unsigned vo = wvoff + (unsigned)((s_) * 4096 + lane * 16); \
        GLD4(V0, vo, sV, 0);    GLD4(V1, vo, sV, 1024); \
        GLD4(V2, vo, sV, 2048); GLD4(V3, vo, sV, 3072); \
    } while (0)
    #define KWR(dst) do { \
        unsigned short* _p = (dst) + kwb; \
        lds_put(_p, K0);        lds_put(_p + 544, K1); \
        lds_put(_p + 1088, K2); lds_put(_p + 1632, K3); \
    } while (0)
    #define VWR(dst) do { \
        unsigned short* _p = (dst) + vwb; \
        lds_put(_p, V0);        lds_put(_p + 576, V1); \
        lds_put(_p + 1152, V2); lds_put(_p + 1728, V3); \
    } while (0)

    KISS(0); VISS(0); WAITVM0(); SBAR();
    KWR(&ksm[w][0][0]); VWR(&vsm[w][0][0]);
    KISS(1); VISS(1);

    f32x16 oacc0 = {}, oacc1 = {};

    for (int s = 0; s < 16; ++s) {
        const unsigned short* Kt = &ksm[w][s & 1][0];
        const unsigned short* Vl = &vsm[w][s & 1][0];
        // ---- S^T ----
        const unsigned short* kp = Kt + l31 * 68 + hi * 8;
        const bf16x8 a0 = lds_frag(kp);
        const bf16x8 a1 = lds_frag(kp + 16);
        const bf16x8 a2 = lds_frag(kp + 32);
        const bf16x8 a3 = lds_frag(kp + 48);
        f32x16 T = {};
        PRIO(1);
        T = MFMA32(a0, qb0, T); T = MFMA32(a1, qb1, T);
        T = MFMA32(a2, qb2, T); T = MFMA32(a3, qb3, T);
        PRIO(0);
        // ---- E -> bf16 B-frags via cvt_pk + permlane32_swap (v9-verified) ----
        unsigned u0 = cvtpk(EXP2(T[0] * C2),  EXP2(T[1] * C2));
        unsigned u1 = cvtpk(EXP2(T[2] * C2),  EXP2(T[3] * C2));
        unsigned u2 = cvtpk(EXP2(T[4] * C2),  EXP2(T[5] * C2));
        unsigned u3 = cvtpk(EXP2(T[6] * C2),  EXP2(T[7] * C2));
        unsigned u4 = cvtpk(EXP2(T[8] * C2),  EXP2(T[9] * C2));
        unsigned u5 = cvtpk(EXP2(T[10] * C2), EXP2(T[11] * C2));
        unsigned u6 = cvtpk(EXP2(T[12] * C2), EXP2(T[13] * C2));
        unsigned u7 = cvtpk(EXP2(T[14] * C2), EXP2(T[15] * C2));
        asm volatile("s_nop 1");
        asm("v_permlane32_swap_b32 %0, %1" : "+v"(u0), "+v"(u2));
        asm("v_permlane32_swap_b32 %0, %1" : "+v"(u1), "+v"(u3));
        asm("v_permlane32_swap_b32 %0, %1" : "+v"(u4), "+v"(u6));
        asm("v_permlane32_swap_b32 %0, %1" : "+v"(u5), "+v"(u7));
        u32x4 f1, f2;
        f1[0] = u0; f1[1] = u1; f1[2] = u2; f1[3] = u3;
        f2[0] = u4; f2[1] = u5; f2[2] = u6; f2[3] = u7;
        // ---- PV ----
        const unsigned short* vp0 = Vl + l31 * 36 + hi * 8;
        const unsigned short* vp1 = Vl + (32 + l31) * 36 + hi * 8;
        const bf16x8 v00 = lds_frag(vp0);
        const bf16x8 v01 = lds_frag(vp0 + 16);
        const bf16x8 v10 = lds_frag(vp1);
        const bf16x8 v11 = lds_frag(vp1 + 16);
        PRIO(1);
        oacc0 = MFMA32(v00, asbf(f1), oacc0);
        oacc0 = MFMA32(v01, asbf(f2), oacc0);
        oacc1 = MFMA32(v10, asbf(f1), oacc1);
        oacc1 = MFMA32(v11, asbf(f2), oacc1);
        PRIO(0);
        // ---- pipeline maintenance ----
        if (s < 15) {
            WAITVM0(); SBAR();              // tile s+1 regs arrived
            KWR(&ksm[w][(s + 1) & 1][0]);
            VWR(&vsm[w][(s + 1) & 1][0]);
            if (s < 14) { KISS(s + 2); VISS(s + 2); }
        }
    }
    #undef KISS
    #undef VISS
    #undef KWR
    #undef VWR

    // combine 8 waves' k-split partials (ocomb aliases ksm)
    __syncthreads();
    float* ocomb = (float*)&ksm[0][0][0];   // [32 q][68]
    for (int i = tid; i < 32 * 68; i += 512) ocomb[i] = 0.f;
    __syncthreads();
    #pragma unroll
    for (int r = 0; r < 16; ++r) {
        const int fr = (r & 3) + 8 * (r >> 2) + 4 * hi;
        atomicAdd(&ocomb[l31 * 68 + fr],      oacc0[r]);
        atomicAdd(&ocomb[l31 * 68 + 32 + fr], oacc1[r]);
    }
    __syncthreads();
    {
        const int q = tid >> 4, fc = tid & 15;       // 32 q x 16 float4
        const size_t row = (size_t)b * LL + q0 + q;
        const float4 xv = ((const float4*)(x + row * CC))[fc];
        const float4 ov = *(const float4*)(&ocomb[q * 68 + fc * 4]);
        ((float4*)(out + row * CC))[fc] =
            make_float4(xv.x + ov.x, xv.y + ov.y, xv.z + ov.z, xv.w + ov.w);
    }
}

extern "C" void kernel_launch(void* const* d_in, const int* in_sizes, int n_in,
                              void* d_out, int out_size, void* d_ws, size_t ws_size,
                              hipStream_t stream)
{
    const float* x  = (const float*)d_in[0];
    const float* Wq = (const float*)d_in[1];
    const float* bq = (const float*)d_in[2];
    const float* Wk = (const float*)d_in[3];
    const float* bk = (const float*)d_in[4];
    const float* Wv = (const float*)d_in[5];
    const float* bv = (const float*)d_in[6];
    float* out = (float*)d_out;

    const size_t n = (size_t)BB * LL * CC;
    unsigned short* Qb = (unsigned short*)d_ws;
    unsigned short* Kb = Qb + n;
    unsigned short* Vt = Kb + n;   // [b][kt32(128)][f(64)][kin(32)]

    hipLaunchKernelGGL(k_qkv, dim3(3 * BB * LL / 64), dim3(512), 0, stream,
                       x, Wq, bq, Wk, bk, Wv, bv, Qb, Kb, Vt);
    hipLaunchKernelGGL(k_stats, dim3(BB * (LL / 32)), dim3(512), 0, stream,
                       Qb, Kb, Vt);
    hipLaunchKernelGGL(k_out, dim3(BB * (LL / 32)), dim3(512), 0, stream,
                       x, Qb, Kb, Vt, out);
}

// Round 12
// 97.065 us; speedup vs baseline: 1.5681x; 1.0756x over previous
//
#include <hip/hip_runtime.h>
#include <math.h>

// Attention1D: B=4, L=4096, C=F=64, fp32 in/out.
// scores=(QK^T)/8; softmax over QUERY axis; out = P@V + x = E@(diag(rl)V) + x.
// v12: k_out re-tiled to 64q/block (2 q-frag sets): 2x MFMA per staged byte,
// half the L2 traffic/CU (1MB). Wave-private SINGLE-buffer LDS tiles (in-order
// per-wave LDS makes write-after-read safe), loads held in regs across the
// compute (T14), zero in-loop barriers. k_stats/k_qkv unchanged from v11.

#define BB 4
#define LL 4096
#define CC 64
#define C2 0.18033688011112042f  // 0.125 * log2(e)

typedef __attribute__((ext_vector_type(8)))  short bf16x8;
typedef __attribute__((ext_vector_type(4)))  float f32x4;
typedef __attribute__((ext_vector_type(16))) float f32x16;
typedef __attribute__((ext_vector_type(4)))  unsigned int u32x4;

#define MFMA16(a, b, c) __builtin_amdgcn_mfma_f32_16x16x32_bf16(a, b, c, 0, 0, 0)
#define MFMA32(a, b, c) __builtin_amdgcn_mfma_f32_32x32x16_bf16(a, b, c, 0, 0, 0)
#define EXP2(x) __builtin_amdgcn_exp2f(x)

#define GLD4(dst, voff, base, imm) \
    asm volatile("global_load_dwordx4 %0, %1, %2 offset:%c3" \
                 : "=v"(dst) : "v"(voff), "s"(base), "i"(imm))
#define WAITVM0() asm volatile("s_waitcnt vmcnt(0)" ::: "memory")
#define SBAR() __builtin_amdgcn_sched_barrier(0)
#define PRIO(n) __builtin_amdgcn_s_setprio(n)

static __device__ __forceinline__ bf16x8 asbf(u32x4 v) {
    union { u32x4 a; bf16x8 b; } u; u.a = v; return u.b;
}
static __device__ __forceinline__ unsigned short f2bf(float f) {
    union { float f; unsigned u; } v; v.f = f;
    unsigned r = v.u + 0x7FFFu + ((v.u >> 16) & 1u);
    return (unsigned short)(r >> 16);
}
static __device__ __forceinline__ float bf2f(unsigned short h) {
    union { unsigned u; float f; } v; v.u = ((unsigned)h) << 16; return v.f;
}
static __device__ __forceinline__ bf16x8 pack8(float4 a, float4 b) {
    bf16x8 r;
    r[0] = (short)f2bf(a.x); r[1] = (short)f2bf(a.y);
    r[2] = (short)f2bf(a.z); r[3] = (short)f2bf(a.w);
    r[4] = (short)f2bf(b.x); r[5] = (short)f2bf(b.y);
    r[6] = (short)f2bf(b.z); r[7] = (short)f2bf(b.w);
    return r;
}
static __device__ __forceinline__ unsigned cvtpk(float lo, float hi) {
    unsigned r;
    asm("v_cvt_pk_bf16_f32 %0, %1, %2" : "=v"(r) : "v"(lo), "v"(hi));
    return r;
}
static __device__ __forceinline__ bf16x8 lds_frag(const unsigned short* p) {
    union { uint2 u[2]; bf16x8 b; } t;
    t.u[0] = *(const uint2*)(p);
    t.u[1] = *(const uint2*)(p + 4);
    return t.b;
}
static __device__ __forceinline__ void lds_put(unsigned short* p, u32x4 v) {
    *(uint2*)(p)     = make_uint2(v[0], v[1]);
    *(uint2*)(p + 4) = make_uint2(v[2], v[3]);
}

// ---------------- K1: projections via MFMA -> bf16 Q, K, V-tiles ----------------
__global__ __launch_bounds__(512) void k_qkv(
    const float* __restrict__ x,
    const float* __restrict__ Wq, const float* __restrict__ bq,
    const float* __restrict__ Wk, const float* __restrict__ bk,
    const float* __restrict__ Wv, const float* __restrict__ bv,
    unsigned short* __restrict__ Qb, unsigned short* __restrict__ Kb,
    unsigned short* __restrict__ Vt)
{
    __shared__ float Wl[64 * 64];
    __shared__ unsigned short ldsV[64 * 72];
    const int bid = blockIdx.x;
    const int mat = bid % 3;          // 0:Q 1:K 2:V
    const int r0 = (bid / 3) * 64;
    const int tid = threadIdx.x, w = tid >> 6, lane = tid & 63;
    const int c = lane & 15, g = lane >> 4;
    const int rw = (w >> 1) * 16;
    const int c0 = (w & 1) * 32;

    const float* W  = (mat == 0) ? Wq : (mat == 1) ? Wk : Wv;
    const float* bs = (mat == 0) ? bq : (mat == 1) ? bk : bv;

    {   // coalesced W stage
        const float4* wsrc = (const float4*)W;
        float4* wdst = (float4*)Wl;
        wdst[tid] = wsrc[tid];
        wdst[tid + 512] = wsrc[tid + 512];
    }

    const float* xr = x + (size_t)(r0 + rw + c) * CC;
    const bf16x8 ax0 = pack8(((const float4*)xr)[2 * g], ((const float4*)xr)[2 * g + 1]);
    const bf16x8 ax1 = pack8(((const float4*)xr)[8 + 2 * g], ((const float4*)xr)[8 + 2 * g + 1]);
    __syncthreads();

    f32x4 acc0 = {0.f, 0.f, 0.f, 0.f}, acc1 = {0.f, 0.f, 0.f, 0.f};
    {
        const int col = c0 + c;
        bf16x8 b0, b1;
        #pragma unroll
        for (int j = 0; j < 8; ++j) {
            b0[j] = (short)f2bf(Wl[(8 * g + j) * 64 + col]);
            b1[j] = (short)f2bf(Wl[(32 + 8 * g + j) * 64 + col]);
        }
        acc0 = MFMA16(ax0, b0, acc0); acc0 = MFMA16(ax1, b1, acc0);
    }
    {
        const int col = c0 + 16 + c;
        bf16x8 b0, b1;
        #pragma unroll
        for (int j = 0; j < 8; ++j) {
            b0[j] = (short)f2bf(Wl[(8 * g + j) * 64 + col]);
            b1[j] = (short)f2bf(Wl[(32 + 8 * g + j) * 64 + col]);
        }
        acc1 = MFMA16(ax0, b0, acc1); acc1 = MFMA16(ax1, b1, acc1);
    }
    const float bias0 = bs[c0 + c], bias1 = bs[c0 + 16 + c];

    if (mat < 2) {
        unsigned short* dst = (mat == 0) ? Qb : Kb;
        #pragma unroll
        for (int r = 0; r < 4; ++r) {
            const size_t row = (size_t)(r0 + rw + 4 * g + r) * CC;
            dst[row + c0 + c]      = f2bf(acc0[r] + bias0);
            dst[row + c0 + 16 + c] = f2bf(acc1[r] + bias1);
        }
    } else {
        #pragma unroll
        for (int r = 0; r < 4; ++r) {
            const int rowin = rw + 4 * g + r;     // k within 64-row group
            ldsV[(c0 + c) * 72 + rowin]      = f2bf(acc0[r] + bias0);
            ldsV[(c0 + 16 + c) * 72 + rowin] = f2bf(acc1[r] + bias1);
        }
        __syncthreads();
        // Vt[b][kt32][f][kin32]: two 4KB tiles per block, fully contiguous
        const int b = r0 >> 12, ktb = (r0 & 4095) >> 5;
        const int h = tid >> 8, f = (tid >> 2) & 63, ch = tid & 3;
        *(uint4*)(Vt + ((size_t)(b * 128 + ktb + h) * 64 + f) * 32 + ch * 8)
            = *(const uint4*)(ldsV + f * 72 + h * 32 + ch * 8);
    }
}

// ---------------- K2: column sums -> rescale V-tiles in place ----------------
// (unchanged from v11)
__global__ __launch_bounds__(512, 4) void k_stats(
    const unsigned short* __restrict__ Qb, const unsigned short* __restrict__ Kb,
    unsigned short* __restrict__ Vt)
{
    const int nb = ((blockIdx.x & 7) << 6) | (blockIdx.x >> 3);  // XCD swizzle (512)
    const int b = nb >> 7, kt32 = nb & 127;
    const int kbase = kt32 * 32;
    const int tid = threadIdx.x, w = tid >> 6, lane = tid & 63;
    const int l31 = lane & 31, hi = lane >> 5;

    __shared__ unsigned short qsm[8][2][32 * 68];   // 69632 B
    __shared__ float pl[8][32];
    __shared__ float rls[32];

    const unsigned short* kr = Kb + ((size_t)b * LL + kbase + l31) * CC + 8 * hi;
    const bf16x8 ak0 = *(const bf16x8*)(kr);
    const bf16x8 ak1 = *(const bf16x8*)(kr + 16);
    const bf16x8 ak2 = *(const bf16x8*)(kr + 32);
    const bf16x8 ak3 = *(const bf16x8*)(kr + 48);

    const unsigned short* const sQ = Qb + (size_t)b * LL * CC;  // block-uniform base
    const unsigned wqoff = (unsigned)(w * 65536);               // wave's 512-q slab (bytes)
    const int wb = (lane >> 3) * 68 + (lane & 7) * 8;
    unsigned short* const q0b = &qsm[w][0][0];
    unsigned short* const q1b = &qsm[w][1][0];

    u32x4 S0, S1, S2, S3;
    #define QISS(s_) do { \
        const unsigned vo = wqoff + (unsigned)((s_) * 4096 + lane * 16); \
        GLD4(S0, vo, sQ, 0);    GLD4(S1, vo, sQ, 1024); \
        GLD4(S2, vo, sQ, 2048); GLD4(S3, vo, sQ, 3072); \
    } while (0)
    #define QWR(dst) do { \
        unsigned short* _p = (dst) + wb; \
        lds_put(_p, S0);        lds_put(_p + 544, S1); \
        lds_put(_p + 1088, S2); lds_put(_p + 1632, S3); \
    } while (0)

    QISS(0); WAITVM0(); SBAR(); QWR(q0b); QISS(1);

    f32x16 lacc = {};
    for (int s = 0; s < 16; ++s) {
        const unsigned short* qp = ((s & 1) ? q1b : q0b) + l31 * 68 + hi * 8;
        const bf16x8 b0 = lds_frag(qp);
        const bf16x8 b1 = lds_frag(qp + 16);
        const bf16x8 b2 = lds_frag(qp + 32);
        const bf16x8 b3 = lds_frag(qp + 48);
        f32x16 T = {};
        PRIO(1);
        T = MFMA32(ak0, b0, T); T = MFMA32(ak1, b1, T);
        T = MFMA32(ak2, b2, T); T = MFMA32(ak3, b3, T);
        PRIO(0);
        #pragma unroll
        for (int r = 0; r < 16; ++r) lacc[r] += EXP2(T[r] * C2);
        if (s < 15) {
            WAITVM0(); SBAR();
            QWR((s & 1) ? q0b : q1b);
            if (s < 14) QISS(s + 2);
        }
    }
    #undef QISS
    #undef QWR

    #pragma unroll
    for (int r = 0; r < 16; ++r) {
        float v = lacc[r];
        v += __shfl_xor(v, 1);  v += __shfl_xor(v, 2);
        v += __shfl_xor(v, 4);  v += __shfl_xor(v, 8);
        v += __shfl_xor(v, 16);
        lacc[r] = v;
    }
    if (l31 == 0) {
        #pragma unroll
        for (int r = 0; r < 16; ++r)
            pl[w][(r & 3) + 8 * (r >> 2) + 4 * hi] = lacc[r];
    }
    __syncthreads();
    if (tid < 32) {
        float L = 0.f;
        #pragma unroll
        for (int ww = 0; ww < 8; ++ww) L += pl[ww][tid];
        rls[tid] = 1.0f / L;
    }
    __syncthreads();

    {
        unsigned short* vbase = Vt + ((size_t)(b * 128 + kt32)) * 2048;
        const int kin0 = (tid & 7) * 4;
        ushort4 v = *(const ushort4*)(vbase + tid * 4);
        v.x = f2bf(bf2f(v.x) * rls[kin0 + 0]);
        v.y = f2bf(bf2f(v.y) * rls[kin0 + 1]);
        v.z = f2bf(bf2f(v.z) * rls[kin0 + 2]);
        v.w = f2bf(bf2f(v.w) * rls[kin0 + 3]);
        *(ushort4*)(vbase + tid * 4) = v;
    }
}

// ---------------- K3: out = E @ V' + x ----------------
// v12: grid = B*(L/64) = 256 blocks x 512 thr (block = 64 q, 2 q-frag sets).
// Wave w owns k in [w*512,(w+1)*512), 16 steps of 32k. SINGLE-buffer
// wave-private K[32][68]+V[64][36] tiles (71.7KB); per step 16 MFMA
// (2x S-tiles + 2x PV) off one set of tile reads; loads held in regs.
__global__ __launch_bounds__(512, 2) void k_out(
    const float* __restrict__ x,
    const unsigned short* __restrict__ Qb, const unsigned short* __restrict__ Kb,
    const unsigned short* __restrict__ Vt,
    float* __restrict__ out)
{
    const int nb = ((blockIdx.x & 7) << 5) | (blockIdx.x >> 3);  // XCD swizzle (256)
    const int b = nb >> 6, qt = nb & 63;
    const int q0 = qt * 64;
    const int tid = threadIdx.x, w = tid >> 6, lane = tid & 63;
    const int l31 = lane & 31, hi = lane >> 5;

    __shared__ unsigned short ksm[8][32 * 68];   // 34816 B
    __shared__ unsigned short vsm[8][64 * 36];   // 36864 B

    // loop-invariant Q B-frags, two q-sets (one-time gather)
    const unsigned short* qrA = Qb + ((size_t)b * LL + q0 + l31) * CC + 8 * hi;
    const unsigned short* qrB = qrA + 32 * CC;
    const bf16x8 qA0 = *(const bf16x8*)(qrA);
    const bf16x8 qA1 = *(const bf16x8*)(qrA + 16);
    const bf16x8 qA2 = *(const bf16x8*)(qrA + 32);
    const bf16x8 qA3 = *(const bf16x8*)(qrA + 48);
    const bf16x8 qB0 = *(const bf16x8*)(qrB);
    const bf16x8 qB1 = *(const bf16x8*)(qrB + 16);
    const bf16x8 qB2 = *(const bf16x8*)(qrB + 32);
    const bf16x8 qB3 = *(const bf16x8*)(qrB + 48);

    const unsigned short* const sK = Kb + (size_t)b * LL * CC;        // block-uniform
    const unsigned short* const sV = Vt + (size_t)b * 128 * 2048;     // block-uniform
    const unsigned wkoff = (unsigned)(w * 65536);   // wave's 512-k K slab (bytes)
    const unsigned wvoff = (unsigned)(w * 65536);   // wave's 16 V tiles (bytes)
    const int kwb = (lane >> 3) * 68 + (lane & 7) * 8;
    const int vwb = (lane >> 2) * 36 + (lane & 3) * 8;

    u32x4 K0, K1, K2, K3, V0, V1, V2, V3;
    #define KISS(s_) do { \
        const unsigned vo = wkoff + (unsigned)((s_) * 4096 + lane * 16); \
        GLD4(K0, vo, sK, 0);    GLD4(K1, vo, sK, 1024); \
        GLD4(K2, vo, sK, 2048); GLD4(K3, vo, sK, 3072); \
    } while (0)
    #define VISS(s_) do { \
        const unsigned vo = wvoff + (unsigned)((s_) * 4096 + lane * 16); \
        GLD4(V0, vo, sV, 0);    GLD4(V1, vo, sV, 1024); \
        GLD4(V2, vo, sV, 2048); GLD4(V3, vo, sV, 3072); \
    } while (0)
    #define KWR() do { \
        unsigned short* _p = &ksm[w][0] + kwb; \
        lds_put(_p, K0);        lds_put(_p + 544, K1); \
        lds_put(_p + 1088, K2); lds_put(_p + 1632, K3); \
    } while (0)
    #define VWR() do { \
        unsigned short* _p = &vsm[w][0] + vwb; \
        lds_put(_p, V0);        lds_put(_p + 576, V1); \
        lds_put(_p + 1152, V2); lds_put(_p + 1728, V3); \
    } while (0)

    KISS(0); VISS(0); WAITVM0(); SBAR();
    KWR(); VWR();
    KISS(1); VISS(1);

    f32x16 oA0 = {}, oA1 = {}, oB0 = {}, oB1 = {};

    for (int s = 0; s < 16; ++s) {
        // ---- S^T tiles for both q-sets off one K-frag read ----
        const unsigned short* kp = &ksm[w][0] + l31 * 68 + hi * 8;
        const bf16x8 a0 = lds_frag(kp);
        const bf16x8 a1 = lds_frag(kp + 16);
        const bf16x8 a2 = lds_frag(kp + 32);
        const bf16x8 a3 = lds_frag(kp + 48);
        f32x16 TA = {}, TB = {};
        PRIO(1);
        TA = MFMA32(a0, qA0, TA); TA = MFMA32(a1, qA1, TA);
        TA = MFMA32(a2, qA2, TA); TA = MFMA32(a3, qA3, TA);
        TB = MFMA32(a0, qB0, TB); TB = MFMA32(a1, qB1, TB);
        TB = MFMA32(a2, qB2, TB); TB = MFMA32(a3, qB3, TB);
        PRIO(0);
        // ---- E -> bf16 B-frags (cvt_pk + permlane32_swap), both sets ----
        unsigned a0u = cvtpk(EXP2(TA[0] * C2),  EXP2(TA[1] * C2));
        unsigned a1u = cvtpk(EXP2(TA[2] * C2),  EXP2(TA[3] * C2));
        unsigned a2u = cvtpk(EXP2(TA[4] * C2),  EXP2(TA[5] * C2));
        unsigned a3u = cvtpk(EXP2(TA[6] * C2),  EXP2(TA[7] * C2));
        unsigned a4u = cvtpk(EXP2(TA[8] * C2),  EXP2(TA[9] * C2));
        unsigned a5u = cvtpk(EXP2(TA[10] * C2), EXP2(TA[11] * C2));
        unsigned a6u = cvtpk(EXP2(TA[12] * C2), EXP2(TA[13] * C2));
        unsigned a7u = cvtpk(EXP2(TA[14] * C2), EXP2(TA[15] * C2));
        unsigned b0u = cvtpk(EXP2(TB[0] * C2),  EXP2(TB[1] * C2));
        unsigned b1u = cvtpk(EXP2(TB[2] * C2),  EXP2(TB[3] * C2));
        unsigned b2u = cvtpk(EXP2(TB[4] * C2),  EXP2(TB[5] * C2));
        unsigned b3u = cvtpk(EXP2(TB[6] * C2),  EXP2(TB[7] * C2));
        unsigned b4u = cvtpk(EXP2(TB[8] * C2),  EXP2(TB[9] * C2));
        unsigned b5u = cvtpk(EXP2(TB[10] * C2), EXP2(TB[11] * C2));
        unsigned b6u = cvtpk(EXP2(TB[12] * C2), EXP2(TB[13] * C2));
        unsigned b7u = cvtpk(EXP2(TB[14] * C2), EXP2(TB[15] * C2));
        asm volatile("s_nop 1");
        asm("v_permlane32_swap_b32 %0, %1" : "+v"(a0u), "+v"(a2u));
        asm("v_permlane32_swap_b32 %0, %1" : "+v"(a1u), "+v"(a3u));
        asm("v_permlane32_swap_b32 %0, %1" : "+v"(a4u), "+v"(a6u));
        asm("v_permlane32_swap_b32 %0, %1" : "+v"(a5u), "+v"(a7u));
        asm("v_permlane32_swap_b32 %0, %1" : "+v"(b0u), "+v"(b2u));
        asm("v_permlane32_swap_b32 %0, %1" : "+v"(b1u), "+v"(b3u));
        asm("v_permlane32_swap_b32 %0, %1" : "+v"(b4u), "+v"(b6u));
        asm("v_permlane32_swap_b32 %0, %1" : "+v"(b5u), "+v"(b7u));
        u32x4 fA1, fA2, fB1, fB2;
        fA1[0] = a0u; fA1[1] = a1u; fA1[2] = a2u; fA1[3] = a3u;
        fA2[0] = a4u; fA2[1] = a5u; fA2[2] = a6u; fA2[3] = a7u;
        fB1[0] = b0u; fB1[1] = b1u; fB1[2] = b2u; fB1[3] = b3u;
        fB2[0] = b4u; fB2[1] = b5u; fB2[2] = b6u; fB2[3] = b7u;
        // ---- PV for both q-sets off one V-frag read ----
        const unsigned short* vp0 = &vsm[w][0] + l31 * 36 + hi * 8;
        const unsigned short* vp1 = &vsm[w][0] + (32 + l31) * 36 + hi * 8;
        const bf16x8 v00 = lds_frag(vp0);
        const bf16x8 v01 = lds_frag(vp0 + 16);
        const bf16x8 v10 = lds_frag(vp1);
        const bf16x8 v11 = lds_frag(vp1 + 16);
        PRIO(1);
        oA0 = MFMA32(v00, asbf(fA1), oA0);
        oA0 = MFMA32(v01, asbf(fA2), oA0);
        oA1 = MFMA32(v10, asbf(fA1), oA1);
        oA1 = MFMA32(v11, asbf(fA2), oA1);
        oB0 = MFMA32(v00, asbf(fB1), oB0);
        oB0 = MFMA32(v01, asbf(fB2), oB0);
        oB1 = MFMA32(v10, asbf(fB1), oB1);
        oB1 = MFMA32(v11, asbf(fB2), oB1);
        PRIO(0);
        // ---- pipeline maintenance (single buffer: safe, wave-private
        //      in-order LDS; these writes alias this step's reads so the
        //      compiler cannot hoist them) ----
        if (s < 15) {
            WAITVM0(); SBAR();              // tile s+1 regs arrived
            KWR(); VWR();
            if (s < 14) { KISS(s + 2); VISS(s + 2); }
        }
    }
    #undef KISS
    #undef VISS
    #undef KWR
    #undef VWR

    // combine 8 waves' k-split partials (ocomb aliases ksm: 17.4KB <= 34.8KB)
    __syncthreads();
    float* ocomb = (float*)&ksm[0][0];   // [64 q][68]
    for (int i = tid; i < 64 * 68; i += 512) ocomb[i] = 0.f;
    __syncthreads();
    #pragma unroll
    for (int r = 0; r < 16; ++r) {
        const int fr = (r & 3) + 8 * (r >> 2) + 4 * hi;
        atomicAdd(&ocomb[l31 * 68 + fr],             oA0[r]);
        atomicAdd(&ocomb[l31 * 68 + 32 + fr],        oA1[r]);
        atomicAdd(&ocomb[(32 + l31) * 68 + fr],      oB0[r]);
        atomicAdd(&ocomb[(32 + l31) * 68 + 32 + fr], oB1[r]);
    }
    __syncthreads();
    {
        const int q = tid >> 3, f8 = (tid & 7) * 8;   // 64 q x 8 f-chunks
        const size_t row = (size_t)b * LL + q0 + q;
        const float4 xv0 = ((const float4*)(x + row * CC))[f8 >> 2];
        const float4 xv1 = ((const float4*)(x + row * CC))[(f8 >> 2) + 1];
        const float4 ov0 = *(const float4*)(&ocomb[q * 68 + f8]);
        const float4 ov1 = *(const float4*)(&ocomb[q * 68 + f8 + 4]);
        ((float4*)(out + row * CC))[f8 >> 2] =
            make_float4(xv0.x + ov0.x, xv0.y + ov0.y, xv0.z + ov0.z, xv0.w + ov0.w);
        ((float4*)(out + row * CC))[(f8 >> 2) + 1] =
            make_float4(xv1.x + ov1.x, xv1.y + ov1.y, xv1.z + ov1.z, xv1.w + ov1.w);
    }
}

extern "C" void kernel_launch(void* const* d_in, const int* in_sizes, int n_in,
                              void* d_out, int out_size, void* d_ws, size_t ws_size,
                              hipStream_t stream)
{
    const float* x  = (const float*)d_in[0];
    const float* Wq = (const float*)d_in[1];
    const float* bq = (const float*)d_in[2];
    const float* Wk = (const float*)d_in[3];
    const float* bk = (const float*)d_in[4];
    const float* Wv = (const float*)d_in[5];
    const float* bv = (const float*)d_in[6];
    float* out = (float*)d_out;

    const size_t n = (size_t)BB * LL * CC;
    unsigned short* Qb = (unsigned short*)d_ws;
    unsigned short* Kb = Qb + n;
    unsigned short* Vt = Kb + n;   // [b][kt32(128)][f(64)][kin(32)]

    hipLaunchKernelGGL(k_qkv, dim3(3 * BB * LL / 64), dim3(512), 0, stream,
                       x, Wq, bq, Wk, bk, Wv, bv, Qb, Kb, Vt);
    hipLaunchKernelGGL(k_stats, dim3(BB * (LL / 32)), dim3(512), 0, stream,
                       Qb, Kb, Vt);
    hipLaunchKernelGGL(k_out, dim3(BB * (LL / 64)), dim3(512), 0, stream,
                       x, Qb, Kb, Vt, out);
}